// Round 9
// baseline (497.261 us; speedup 1.0000x reference)
//
#include <hip/hip_runtime.h>

// ---------------------------------------------------------------------------
// RGAT encoder: N=50000, E=800000, R=8, IN=H=128, B=10.
// R9 = R8 + occupancy & dispatch-count fixes:
//   k_xw: 64 nodes/block (782 blocks ~ 3/CU), SINGLE 32 KB W buffer,
//         reg-prefetch + 2 barriers/relation. Permuted 64B/lane stores (R8).
//   k_wprep: fuses WTf build + wqk build + deg zeroing (1 dispatch).
//   k_scanC: fuses scanB (block prefix over bsum) + cursor init (=rowptr),
//            so k_scatter uses absolute positions; no cursor memset.
// k_aggr (R8 permuted epilogue) and k_gemmL unchanged. 10 dispatches total.
// ---------------------------------------------------------------------------

typedef unsigned int uint;
typedef unsigned short ushort_t;

using bf16x8 = __attribute__((ext_vector_type(8))) __bf16;
using f32x4  = __attribute__((ext_vector_type(4))) float;

__device__ __forceinline__ ushort_t fToBf(float f) {
  uint u = __float_as_uint(f);
  u += 0x7FFFu + ((u >> 16) & 1);   // round-to-nearest-even
  return (ushort_t)(u >> 16);
}
__device__ __forceinline__ float bfToF(ushort_t h) {
  return __uint_as_float(((uint)h) << 16);
}
__device__ __forceinline__ uint packBf(float a, float b) {
  return (uint)fToBf(a) | ((uint)fToBf(b) << 16);
}

// ------------------------------- CSR build ---------------------------------

__global__ void k_count(const int* __restrict__ tgt, int* __restrict__ deg, int E) {
  int e = blockIdx.x * 256 + threadIdx.x;
  if (e < E) atomicAdd(&deg[tgt[e]], 1);
}

__global__ void k_scanA(const int* __restrict__ deg, int* __restrict__ incl,
                        int* __restrict__ bsum, int n) {
  __shared__ int s[256];
  int tid = threadIdx.x;
  int i = blockIdx.x * 256 + tid;
  int v = (i < n) ? deg[i] : 0;
  s[tid] = v;
  __syncthreads();
  for (int off = 1; off < 256; off <<= 1) {
    int t = (tid >= off) ? s[tid - off] : 0;
    __syncthreads();
    s[tid] += t;
    __syncthreads();
  }
  if (i < n) incl[i] = s[tid];
  if (tid == 255) bsum[blockIdx.x] = s[255];
}

// Fused scanB+scanC: block prefix over bsum (nb <= 256), writes rowptr AND
// initializes cursor = rowptr so scatter can use absolute positions.
__global__ void k_scanC(const int* __restrict__ deg, const int* __restrict__ incl,
                        const int* __restrict__ bsum, int* __restrict__ rowptr,
                        int* __restrict__ cursor, int n, int E, int nb) {
  __shared__ int s[256];
  int tid = threadIdx.x;
  s[tid] = (tid < nb && tid < (int)blockIdx.x) ? bsum[tid] : 0;
  __syncthreads();
  #pragma unroll
  for (int off = 128; off; off >>= 1) {
    if (tid < off) s[tid] += s[tid + off];
    __syncthreads();
  }
  int prefix = s[0];
  int i = blockIdx.x * 256 + tid;
  if (i < n) {
    int rp = prefix + incl[i] - deg[i];   // exclusive scan
    rowptr[i] = rp;
    cursor[i] = rp;
    if (i == n - 1) rowptr[n] = E;
  }
}

__global__ void k_scatter(const int* __restrict__ src, const int* __restrict__ tgt,
                          const int* __restrict__ et, int* __restrict__ cursor,
                          int* __restrict__ sorted, int E) {
  int e = blockIdx.x * 256 + threadIdx.x;
  if (e >= E) return;
  int pos = atomicAdd(&cursor[tgt[e]], 1);   // absolute position
  sorted[pos] = src[e] | (et[e] << 16);      // src < 65536, rel < 8
}

// ------------------------------ weight prep --------------------------------
// One dispatch: blocks 0..127 build WTf (fragment-order W), blocks 128..143
// build wqk, blocks 144..151 zero deg (grid-stride).
// WTf[layer][r][f=mt*4+kb][lane][j] = W[r][kb*32+(lane>>4)*8+j][mt*16+(lane&15)]

__global__ void k_wprep(const float* __restrict__ W1, const float* __restrict__ q1,
                        const float* __restrict__ k1, const float* __restrict__ W2,
                        const float* __restrict__ q2, const float* __restrict__ k2,
                        ushort_t* __restrict__ WTf, ushort_t* __restrict__ wqk,
                        int* __restrict__ deg, int n) {
  int blk = blockIdx.x;
  if (blk < 128) {
    int b = blk * 4 + (threadIdx.x >> 6);   // layer*256 + r*32 + f
    int lane = threadIdx.x & 63;
    int layer = b >> 8;
    int r = (b >> 5) & 7;
    int f = b & 31;
    int mt = f >> 2, kb = f & 3;
    const float* W = layer ? W2 : W1;
    int col = mt * 16 + (lane & 15);
    int krow = kb * 32 + (lane >> 4) * 8;
    ushort_t* dst = WTf + ((size_t)b * 64 + lane) * 8;
    #pragma unroll
    for (int j = 0; j < 8; j++)
      dst[j] = fToBf(W[((size_t)r * 128 + krow + j) * 128 + col]);
  } else if (blk < 144) {
    int g = (blk - 128) * 256 + threadIdx.x;   // 0..4095
    int layer = g >> 11;
    int which = (g >> 10) & 1;
    int idx = g & 1023;                        // r*128 + kin
    const float* w = (layer ? W2 : W1) + (size_t)idx * 128;
    const float* v = layer ? (which ? k2 : q2) : (which ? k1 : q1);
    float s = 0.f;
    #pragma unroll 8
    for (int h = 0; h < 128; h++) s += w[h] * v[h];
    int r = idx >> 7, kin = idx & 127;
    wqk[(size_t)layer * 2048 + ((which << 3) + r) * 128 + kin] = fToBf(s);
  } else {
    for (int i = (blk - 144) * 256 + threadIdx.x; i < n; i += 8 * 256)
      deg[i] = 0;
  }
}

// ------------------------------ xW producer --------------------------------
// Block = 256 thr = 4 waves = 64 nodes (1 tile/wave). Loops all 8 relations;
// x-frags in regs (read once); W[r] in a SINGLE 32 KB LDS buffer in fragment
// order; next relation prefetched to regs during compute, restaged with 2
// barriers. Results packed in regs; permuted stores (64 contiguous B/lane).
// Fragment conventions (R1/R2-verified): A-frag m=lane&15, k=quad*8+j;
// B-frag n=lane&15, k=quad*8+j; C/D row(m)=quad*4+reg, col(n)=lane&15.

template <bool F32IN>
__global__ __launch_bounds__(256) void
k_xw(const void* __restrict__ Ain,          // [M][128] f32 or bf16 node feats
     const ushort_t* __restrict__ WTf,      // [8][32][64][8] this layer
     const ushort_t* __restrict__ Wqk,      // [16][128] this layer
     ushort_t* __restrict__ xW,             // [8][M][128] out, permuted rows
     float* __restrict__ stbl,              // [M][16] out
     int M) {
  __shared__ __align__(16) ushort_t wbuf[16384];   // 32 KB
  int tid = threadIdx.x, wv = tid >> 6, lane = tid & 63;
  int l15 = lane & 15, quad = lane >> 4;
  int node = blockIdx.x * 64 + wv * 16 + l15;
  int nc = node < M ? node : M - 1;

  // B-frags: this lane's node row (registers for all 8 relations + scores)
  bf16x8 bx[4];
  if (F32IN) {
    const float* row = (const float*)Ain + (size_t)nc * 128;
    #pragma unroll
    for (int kb = 0; kb < 4; kb++) {
      float4 a = *(const float4*)(row + kb * 32 + quad * 8);
      float4 b = *(const float4*)(row + kb * 32 + quad * 8 + 4);
      union { bf16x8 v; ushort_t u[8]; } t;
      t.u[0] = fToBf(a.x); t.u[1] = fToBf(a.y); t.u[2] = fToBf(a.z); t.u[3] = fToBf(a.w);
      t.u[4] = fToBf(b.x); t.u[5] = fToBf(b.y); t.u[6] = fToBf(b.z); t.u[7] = fToBf(b.w);
      bx[kb] = t.v;
    }
  } else {
    const ushort_t* row = (const ushort_t*)Ain + (size_t)nc * 128;
    #pragma unroll
    for (int kb = 0; kb < 4; kb++)
      bx[kb] = *(const bf16x8*)(row + kb * 32 + quad * 8);
  }

  // stage W[0] (flat 32 KB copy)
  #pragma unroll
  for (int i = 0; i < 8; i++)
    *(int4*)(wbuf + (size_t)(tid + i * 256) * 8) =
        *(const int4*)(WTf + (size_t)(tid + i * 256) * 8);
  __syncthreads();

  for (int r = 0; r < 8; r++) {
    // prefetch W[r+1] into registers (hidden behind compute)
    int4 pf[8];
    if (r < 7) {
      const ushort_t* src = WTf + (size_t)(r + 1) * 16384;
      #pragma unroll
      for (int i = 0; i < 8; i++)
        pf[i] = *(const int4*)(src + (size_t)(tid + i * 256) * 8);
    }
    uint2 po[8];   // packed bf16: po[mt] = channels mt*16+quad*4+[0..3]
    #pragma unroll
    for (int mt = 0; mt < 8; mt++) {
      f32x4 a = {};
      #pragma unroll
      for (int kb = 0; kb < 4; kb++) {
        bf16x8 af = *(const bf16x8*)(wbuf + (size_t)((mt * 4 + kb) * 64 + lane) * 8);
        a = __builtin_amdgcn_mfma_f32_16x16x32_bf16(af, bx[kb], a, 0, 0, 0);
      }
      po[mt].x = packBf(a[0], a[1]);
      po[mt].y = packBf(a[2], a[3]);
    }
    // permuted store: lane covers bytes [quad*64, quad*64+64) of its node row
    if (node < M) {
      ushort_t* rowp = xW + ((size_t)r * M + node) * 128 + quad * 32;
      #pragma unroll
      for (int i = 0; i < 4; i++) {
        int4 v = {(int)po[2 * i].x, (int)po[2 * i].y,
                  (int)po[2 * i + 1].x, (int)po[2 * i + 1].y};
        *(int4*)(rowp + i * 8) = v;
      }
    }
    if (r < 7) {
      __syncthreads();   // all waves done reading wbuf
      #pragma unroll
      for (int i = 0; i < 8; i++)
        *(int4*)(wbuf + (size_t)(tid + i * 256) * 8) = pf[i];
      __syncthreads();   // restage visible
    }
  }

  // score pass: stbl[node][0..7] = x.Wq[r], [8..15] = x.Wk[r]
  bf16x8 aq[4];
  #pragma unroll
  for (int kb = 0; kb < 4; kb++)
    aq[kb] = *(const bf16x8*)(Wqk + (size_t)l15 * 128 + kb * 32 + quad * 8);
  f32x4 s = {};
  #pragma unroll
  for (int kb = 0; kb < 4; kb++)
    s = __builtin_amdgcn_mfma_f32_16x16x32_bf16(aq[kb], bx[kb], s, 0, 0, 0);
  if (node < M) {
    float4 v = {s[0], s[1], s[2], s[3]};
    *(float4*)(stbl + (size_t)node * 16 + quad * 4) = v;
  }
}

// -------------------- fused softmax + weighted aggregation -----------------
// R8-proven gather (position-agnostic over permuted rows). Epilogue maps
// positions back to channels via base0 = (fcol&3)*32 + (fcol>>2)*4;
// h written in STANDARD channel order.

#define ACC8(W_, V_)                                                     \
  acc[0] += W_ * bfToF((ushort_t)(V_.x & 0xFFFF));                       \
  acc[1] += W_ * bfToF((ushort_t)(V_.x >> 16));                          \
  acc[2] += W_ * bfToF((ushort_t)(V_.y & 0xFFFF));                       \
  acc[3] += W_ * bfToF((ushort_t)(V_.y >> 16));                          \
  acc[4] += W_ * bfToF((ushort_t)(V_.z & 0xFFFF));                       \
  acc[5] += W_ * bfToF((ushort_t)(V_.z >> 16));                          \
  acc[6] += W_ * bfToF((ushort_t)(V_.w & 0xFFFF));                       \
  acc[7] += W_ * bfToF((ushort_t)(V_.w >> 16));

__global__ __launch_bounds__(256) void
k_aggr(const ushort_t* __restrict__ feat,   // [R*N][128] bf16 (= xW, permuted)
       const float* __restrict__ stbl,      // [N][16]: 0..7 q-side, 8..15 k-side
       const int* __restrict__ rowptr, const int* __restrict__ sorted,
       const float* __restrict__ bias, ushort_t* __restrict__ outp, int n) {
  int tid = threadIdx.x, wv = tid >> 6, lane = tid & 63;
  int t = blockIdx.x * 4 + wv;
  if (t >= n) return;
  int e0 = rowptr[t], e1 = rowptr[t + 1];
  int g4 = lane >> 4, fcol = lane & 15;

  float m = -INFINITY, den = 0.f;
  float acc[8] = {};

  for (int base = e0; base < e1; base += 64) {
    int cnt = min(64, e1 - base);
    float alpha = -INFINITY;
    int pk = 0;
    if (lane < cnt) {
      pk = sorted[base + lane];
      int s = pk & 0xFFFF, r = pk >> 16;
      float a = stbl[(size_t)t * 16 + r] + stbl[(size_t)s * 16 + 8 + r];
      alpha = (a >= 0.f) ? a : 0.2f * a;   // leaky_relu 0.2
    }
    float cm = alpha;
    #pragma unroll
    for (int off = 32; off; off >>= 1) cm = fmaxf(cm, __shfl_xor(cm, off, 64));
    float nm = fmaxf(m, cm);
    float sc = __expf(m - nm);
    den *= sc;
    #pragma unroll
    for (int i = 0; i < 8; i++) acc[i] *= sc;
    float w = (lane < cnt) ? __expf(alpha - nm) : 0.f;
    float ws = w;
    #pragma unroll
    for (int off = 32; off; off >>= 1) ws += __shfl_xor(ws, off, 64);
    den += ws;
    m = nm;

    for (int g = 0; g < cnt; g += 16) {    // 16 edges/iter, 4 dwordx4 in flight
      int i0 = g + g4;
      float w0 = __shfl(w, i0, 64);
      float w1 = __shfl(w, i0 + 4, 64);
      float w2 = __shfl(w, i0 + 8, 64);
      float w3 = __shfl(w, i0 + 12, 64);
      int p0 = __shfl(pk, i0, 64);
      int p1 = __shfl(pk, i0 + 4, 64);
      int p2 = __shfl(pk, i0 + 8, 64);
      int p3 = __shfl(pk, i0 + 12, 64);
      const uint4* r0 = (const uint4*)(feat + (size_t)((p0 >> 16) * n + (p0 & 0xFFFF)) * 128) + fcol;
      const uint4* r1 = (const uint4*)(feat + (size_t)((p1 >> 16) * n + (p1 & 0xFFFF)) * 128) + fcol;
      const uint4* r2 = (const uint4*)(feat + (size_t)((p2 >> 16) * n + (p2 & 0xFFFF)) * 128) + fcol;
      const uint4* r3 = (const uint4*)(feat + (size_t)((p3 >> 16) * n + (p3 & 0xFFFF)) * 128) + fcol;
      uint4 v0 = *r0;
      uint4 v1 = *r1;
      uint4 v2 = *r2;
      uint4 v3 = *r3;
      ACC8(w0, v0)
      ACC8(w1, v1)
      ACC8(w2, v2)
      ACC8(w3, v3)
    }
  }

  #pragma unroll
  for (int i = 0; i < 8; i++) acc[i] += __shfl_xor(acc[i], 16, 64);
  #pragma unroll
  for (int i = 0; i < 8; i++) acc[i] += __shfl_xor(acc[i], 32, 64);

  float inv = (den > 0.f) ? 1.f / (den + 1e-16f) : 0.f;
  // un-permute: acc[0..3] -> channels base0+[0..3], acc[4..7] -> base0+16+[0..3]
  int base0 = (fcol & 3) * 32 + (fcol >> 2) * 4;
  float4 ba = *(const float4*)(bias + base0);
  float4 bb = *(const float4*)(bias + base0 + 16);
  uint2 oa, ob;
  oa.x = packBf(fmaxf(acc[0] * inv + ba.x, 0.f), fmaxf(acc[1] * inv + ba.y, 0.f));
  oa.y = packBf(fmaxf(acc[2] * inv + ba.z, 0.f), fmaxf(acc[3] * inv + ba.w, 0.f));
  ob.x = packBf(fmaxf(acc[4] * inv + bb.x, 0.f), fmaxf(acc[5] * inv + bb.y, 0.f));
  ob.y = packBf(fmaxf(acc[6] * inv + bb.z, 0.f), fmaxf(acc[7] * inv + bb.w, 0.f));
  if (lane < 16) {
    *(uint2*)(outp + (size_t)t * 128 + base0) = oa;
    *(uint2*)(outp + (size_t)t * 128 + base0 + 16) = ob;
  }
}

// ----------------------------- final linear --------------------------------

#define LDA 136

__global__ __launch_bounds__(256) void
k_gemmL(const ushort_t* __restrict__ A, const float* __restrict__ Wl,
        float* __restrict__ Cout, const float* __restrict__ bias, int M) {
  __shared__ ushort_t As[64 * LDA];
  __shared__ ushort_t Bs[128 * LDA];
  int tid = threadIdx.x;
  int row0 = blockIdx.x * 64;
  for (int c = tid; c < 1024; c += 256) {
    int r = c >> 4, off = (c & 15) * 8;
    int4 v = {0, 0, 0, 0};
    if (row0 + r < M) v = *(const int4*)(A + (size_t)(row0 + r) * 128 + off);
    *(int4*)(As + r * LDA + off) = v;
  }
  for (int c = tid; c < 2048; c += 256) {
    int nn = c >> 4, off = (c & 15) * 8;
    float4 a = *(const float4*)(Wl + (size_t)nn * 128 + off);
    float4 b = *(const float4*)(Wl + (size_t)nn * 128 + off + 4);
    ushort_t* d = Bs + nn * LDA + off;
    d[0] = fToBf(a.x); d[1] = fToBf(a.y); d[2] = fToBf(a.z); d[3] = fToBf(a.w);
    d[4] = fToBf(b.x); d[5] = fToBf(b.y); d[6] = fToBf(b.z); d[7] = fToBf(b.w);
  }
  __syncthreads();
  int wv = tid >> 6, lane = tid & 63;
  int l15 = lane & 15, quad = lane >> 4;
  int wr = wv * 16;
  bf16x8 afr[4];
  #pragma unroll
  for (int kb = 0; kb < 4; kb++)
    afr[kb] = *reinterpret_cast<const bf16x8*>(As + (wr + l15) * LDA + kb * 32 + quad * 8);
  f32x4 acc[8] = {};
  #pragma unroll
  for (int ct = 0; ct < 8; ct++)
    #pragma unroll
    for (int kb = 0; kb < 4; kb++) {
      bf16x8 bfr = *reinterpret_cast<const bf16x8*>(Bs + (ct * 16 + l15) * LDA + kb * 32 + quad * 8);
      acc[ct] = __builtin_amdgcn_mfma_f32_16x16x32_bf16(afr[kb], bfr, acc[ct], 0, 0, 0);
    }
  #pragma unroll
  for (int ct = 0; ct < 8; ct++)
    #pragma unroll
    for (int reg = 0; reg < 4; reg++) {
      int rr = row0 + wr + quad * 4 + reg;
      if (rr < M) Cout[(size_t)rr * 128 + ct * 16 + l15] = acc[ct][reg] + bias[ct * 16 + l15];
    }
}

// ------------------------------- launcher ----------------------------------

extern "C" void kernel_launch(void* const* d_in, const int* in_sizes, int n_in,
                              void* d_out, int out_size, void* d_ws, size_t ws_size,
                              hipStream_t stream) {
  const float* x   = (const float*)d_in[0];
  const int* ei    = (const int*)d_in[1];
  const int* etype = (const int*)d_in[2];
  const float* W1  = (const float*)d_in[4];
  const float* q1  = (const float*)d_in[5];
  const float* k1  = (const float*)d_in[6];
  const float* b1  = (const float*)d_in[7];
  const float* W2  = (const float*)d_in[8];
  const float* q2  = (const float*)d_in[9];
  const float* k2  = (const float*)d_in[10];
  const float* b2  = (const float*)d_in[11];
  const float* Wl  = (const float*)d_in[12];
  const float* bl  = (const float*)d_in[13];
  float* out       = (float*)d_out;

  const int N = in_sizes[0] / 128;   // 50000
  const int E = in_sizes[2];         // 800000

  char* ws = (char*)d_ws;
  size_t off = 0;
  auto alloc = [&](size_t bytes) {
    size_t o = off;
    off = (off + bytes + 255) & ~(size_t)255;
    return o;
  };

  ushort_t* xW    = (ushort_t*)(ws + alloc((size_t)8 * N * 128 * 2));
  ushort_t* h1    = (ushort_t*)(ws + alloc((size_t)N * 128 * 2));
  ushort_t* h2    = (ushort_t*)(ws + alloc((size_t)N * 128 * 2));
  ushort_t* WTf   = (ushort_t*)(ws + alloc((size_t)2 * 8 * 16384 * 2));
  ushort_t* wqk   = (ushort_t*)(ws + alloc(2 * 16 * 128 * 2));
  float* stblA    = (float*)(ws + alloc((size_t)N * 16 * 4));
  float* stblB    = (float*)(ws + alloc((size_t)N * 16 * 4));
  int* deg        = (int*)(ws + alloc((size_t)N * 4));
  int* cursor     = (int*)(ws + alloc((size_t)N * 4));
  int* incl       = (int*)(ws + alloc((size_t)N * 4));
  int* rowptr     = (int*)(ws + alloc((size_t)(N + 1) * 4));
  int* bsum       = (int*)(ws + alloc(256 * 4));
  int* sorted     = (int*)(ws + alloc((size_t)E * 4));
  (void)ws_size; (void)n_in; (void)out_size;

  const int* srcp = ei;
  const int* tgtp = ei + E;

  int gE = (E + 255) / 256;      // 3125
  int gN = (N + 255) / 256;      // 196
  int gW = (N + 3) / 4;          // k_aggr: 12500
  int gX = (N + 63) / 64;        // k_xw: 782
  int gL = (N + 63) / 64;        // k_gemmL: 782

  // weight prep + deg zeroing (1 dispatch, runs before CSR count)
  k_wprep<<<152, 256, 0, stream>>>(W1, q1, k1, W2, q2, k2, WTf, wqk, deg, N);

  // CSR build (once; same graph both layers)
  k_count<<<gE, 256, 0, stream>>>(tgtp, deg, E);
  k_scanA<<<gN, 256, 0, stream>>>(deg, incl, bsum, N);
  k_scanC<<<gN, 256, 0, stream>>>(deg, incl, bsum, rowptr, cursor, N, E, gN);
  k_scatter<<<gE, 256, 0, stream>>>(srcp, tgtp, etype, cursor, sorted, E);

  // layer 1 (reads f32 x directly; emits xW + stblA)
  k_xw<true><<<gX, 256, 0, stream>>>(x, WTf, wqk, xW, stblA, N);
  k_aggr<<<gW, 256, 0, stream>>>(xW, stblA, rowptr, sorted, b1, h1, N);

  // layer 2
  k_xw<false><<<gX, 256, 0, stream>>>(h1, WTf + (size_t)8 * 16384,
                                      wqk + 2048, xW, stblB, N);
  k_aggr<<<gW, 256, 0, stream>>>(xW, stblB, rowptr, sorted, b2, h2, N);

  // final linear
  k_gemmL<<<gL, 256, 0, stream>>>(h2, Wl, out, bl, N);
}